// Round 3
// baseline (268.405 us; speedup 1.0000x reference)
//
#include <hip/hip_runtime.h>
#include <math.h>

static constexpr int NPT = 98;
static constexpr int SEGSLOTS = 280;    // staggered bases, 275 used + pad
static constexpr float CSCALE = 0.310128480f;  // sqrt(log2(e)/15)

#if __has_builtin(__builtin_amdgcn_exp2f)
#define EXP2F(x) __builtin_amdgcn_exp2f(x)
#else
#define EXP2F(x) exp2f(x)
#endif

// LDS layout (float4 slots), one batch element per 64-thread block.
// Each curve: M segments + dup of first M/2 (wrap-free circulant reads).
// Bases staggered so concurrent phase-B lane-groups start in distinct
// bank octants (slot%8): c1=96(0) c2=121(1) c3=146(2) c4=171(3)
//                        c5=193(1) c6=215(7) c7=248(0)
//  c0: base   0, M=64 -> [0,96)
//  c1: base  96, M=16 -> [96,120)
//  c2: base 121, M=16 -> [121,145)
//  c3: base 146, M=16 -> [146,170)
//  c4: base 171, M=14 -> [171,192)
//  c5: base 193, M=14 -> [193,214)
//  c6: base 215, M=22 -> [215,248)
//  c7: base 248, M=18 -> [248,275)

__device__ __forceinline__ float pair_term(float4 si, float4 sj) {
    float dx = si.x - sj.x;
    float dy = si.y - sj.y;
    float d2s = dx * dx + dy * dy;           // pre-scaled by log2e/sigma
    float dt = si.z * sj.z + si.w * sj.w;
    return EXP2F(-d2s) * dt;
}

__global__ __launch_bounds__(64, 8)
void lddmm_main(const float* __restrict__ pred, const float* __restrict__ gt,
                float* __restrict__ ws) {
    __shared__ float4 sg[SEGSLOTS];
    const int lane = threadIdx.x;
    const int b = blockIdx.x;

    const float2* p = (const float2*)(pred + (size_t)b * (2 * NPT));
    const float2* g = (const float2*)(gt + (size_t)b * (2 * NPT));

    // eye-corner loads issued early (consumed at the very end)
    float2 e0 = g[60];
    float2 e1 = g[72];

    float accS = 0.0f;   // x1 bucket
    float accD = 0.0f;   // x2 bucket
    float dsum = 0.0f;

    // ---- staging: 180 segments (+ dup of p-halves), 3 passes
    #pragma unroll
    for (int pass = 0; pass < 3; ++pass) {
        int s = lane + 64 * pass;
        if (s < 180) {
            int A, NS, B, rel;
            if (s < 64)       { A = 0;  NS = 32; B = 0;   rel = s; }
            else if (s < 80)  { A = 33; NS = 8;  B = 96;  rel = s - 64; }
            else if (s < 96)  { A = 42; NS = 8;  B = 121; rel = s - 80; }
            else if (s < 112) { A = 51; NS = 8;  B = 146; rel = s - 96; }
            else if (s < 126) { A = 60; NS = 7;  B = 171; rel = s - 112; }
            else if (s < 140) { A = 68; NS = 7;  B = 193; rel = s - 126; }
            else if (s < 162) { A = 76; NS = 11; B = 215; rel = s - 140; }
            else              { A = 88; NS = 9;  B = 248; rel = s - 162; }
            bool isg = rel >= NS;
            int a = A + (isg ? rel - NS : rel);
            const float2* src = isg ? g : p;
            float2 q0 = src[a];
            float2 q1 = src[a + 1];
            float cx = 0.5f * (q0.x + q1.x) * CSCALE;
            float cy = 0.5f * (q0.y + q1.y) * CSCALE;
            float tx = q1.x - q0.x;
            float ty = q1.y - q0.y;
            if (isg) { tx = -tx; ty = -ty; }
            float4 v = make_float4(cx, cy, tx, ty);
            sg[B + rel] = v;
            if (!isg) sg[B + 2 * NS + rel] = v;   // dup first half (p-segs)
            accS += tx * tx + ty * ty;            // diagonal terms (w=1)
        }
    }
    if (lane < 5) sg[275 + lane] = make_float4(0.f, 0.f, 0.f, 0.f);

    // ---- landmark mean distance
    #pragma unroll
    for (int pass = 0; pass < 2; ++pass) {
        int t = lane + 64 * pass;
        if (t < NPT) {
            float2 pp = p[t];
            float2 gg = g[t];
            float dx = pp.x - gg.x;
            float dy = pp.y - gg.y;
            dsum += sqrtf(dx * dx + dy * dy);
        }
    }

    __syncthreads();  // single wave: degenerates to a waitcnt

    // ---- phase A: curve 0 (M=64), circulant, wrap-free via dup
    {
        const float4* sp = sg + lane;
        float4 sj = sp[0];
        #pragma unroll
        for (int t = 1; t <= 31; ++t) accD += pair_term(sp[t], sj);  // x2
        accS += pair_term(sp[32], sj);                               // x1
    }

    // ---- phase B plan 1: c1,c2,c3 (M=16) + c4 (M=14), t=1..8
    {
        int addr; float hp1;
        if (lane < 16)      { addr = 96 + lane;         hp1 = 9.f; }
        else if (lane < 32) { addr = 121 + (lane - 16); hp1 = 9.f; }
        else if (lane < 48) { addr = 146 + (lane - 32); hp1 = 9.f; }
        else if (lane < 62) { addr = 171 + (lane - 48); hp1 = 8.f; }
        else                { addr = 0;                 hp1 = 0.f; }
        const float4* sp = sg + addr;
        float4 sj = sp[0];
        #pragma unroll
        for (int t = 1; t <= 8; ++t) {
            float m = fminf(fmaxf(hp1 - (float)t, 0.f), 2.f);
            accS = fmaf(m, pair_term(sp[t], sj), accS);
        }
    }

    // ---- phase B plan 2: c5 (M=14), c6 (M=22), c7 (M=18), t=1..11
    {
        int addr; float hp1;
        if (lane < 14)      { addr = 193 + lane;        hp1 = 8.f;  }
        else if (lane < 36) { addr = 215 + (lane - 14); hp1 = 12.f; }
        else if (lane < 54) { addr = 248 + (lane - 36); hp1 = 10.f; }
        else                { addr = 0;                 hp1 = 0.f;  }
        const float4* sp = sg + addr;
        float4 sj = sp[0];
        #pragma unroll
        for (int t = 1; t <= 11; ++t) {
            float m = fminf(fmaxf(hp1 - (float)t, 0.f), 2.f);
            accS = fmaf(m, pair_term(sp[t], sj), accS);
        }
    }

    // per-lane combine, one wave reduction
    float v = 0.8f * dsum + 0.2f * (accS + 2.0f * accD);
    #pragma unroll
    for (int off = 32; off >= 1; off >>= 1) v += __shfl_xor(v, off, 64);

    if (lane == 0) {
        float ex = e0.x - e1.x;
        float ey = e0.y - e1.y;
        float eye = sqrtf(ex * ex + ey * ey);
        ws[b] = v / ((float)NPT * eye);
    }
}

__global__ __launch_bounds__(1024)
void lddmm_reduce(const float* __restrict__ ws, float* __restrict__ out,
                  int n, float invbatch) {
    __shared__ float sm[1024];
    const int t = threadIdx.x;
    float s = 0.0f;
    for (int i = t; i < n; i += 1024) s += ws[i];
    sm[t] = s;
    __syncthreads();
    for (int off = 512; off >= 1; off >>= 1) {
        if (t < off) sm[t] += sm[t + off];
        __syncthreads();
    }
    if (t == 0) out[0] = sm[0] * invbatch;
}

extern "C" void kernel_launch(void* const* d_in, const int* in_sizes, int n_in,
                              void* d_out, int out_size, void* d_ws, size_t ws_size,
                              hipStream_t stream) {
    const float* pred = (const float*)d_in[0];
    const float* gt = (const float*)d_in[1];
    float* out = (float*)d_out;
    float* ws = (float*)d_ws;
    const int batch = in_sizes[0] / (2 * NPT);

    lddmm_main<<<batch, 64, 0, stream>>>(pred, gt, ws);
    lddmm_reduce<<<1, 1024, 0, stream>>>(ws, out, batch, 1.0f / (float)batch);
}

// Round 4
// 29.415 us; speedup vs baseline: 9.1248x; 9.1248x over previous
//
#include <hip/hip_runtime.h>
#include <math.h>

static constexpr int NPT = 98;
static constexpr int SEGSLOTS = 280;    // staggered bases, 275 used + pad
static constexpr float CSCALE = 0.310128480f;  // sqrt(log2(e)/15)

#if __has_builtin(__builtin_amdgcn_exp2f)
#define EXP2F(x) __builtin_amdgcn_exp2f(x)
#else
#define EXP2F(x) exp2f(x)
#endif

// LDS layout (float4 slots), one batch element per 64-thread block.
// Each curve: M segments + dup of first M/2 (wrap-free circulant reads).
//  c0: base   0, M=64 -> [0,96)
//  c1: base  96, M=16 -> [96,120)
//  c2: base 121, M=16 -> [121,145)
//  c3: base 146, M=16 -> [146,170)
//  c4: base 171, M=14 -> [171,192)
//  c5: base 193, M=14 -> [193,214)
//  c6: base 215, M=22 -> [215,248)
//  c7: base 248, M=18 -> [248,275)

__device__ __forceinline__ float pair_term(float4 si, float4 sj) {
    float dx = si.x - sj.x;
    float dy = si.y - sj.y;
    float d2s = dx * dx + dy * dy;           // pre-scaled by log2e/sigma
    float dt = si.z * sj.z + si.w * sj.w;
    return EXP2F(-d2s) * dt;
}

__global__ __launch_bounds__(64, 4)   // cap 128 VGPR: above natural use -> no spill
void lddmm_main(const float* __restrict__ pred, const float* __restrict__ gt,
                float* __restrict__ ws) {
    __shared__ float4 sg[SEGSLOTS];
    const int lane = threadIdx.x;
    const int b = blockIdx.x;

    const float2* p = (const float2*)(pred + (size_t)b * (2 * NPT));
    const float2* g = (const float2*)(gt + (size_t)b * (2 * NPT));

    // eye-corner loads issued early (consumed at the very end)
    float2 e0 = g[60];
    float2 e1 = g[72];

    float accS = 0.0f;   // x1 bucket
    float accD = 0.0f;   // x2 bucket
    float dsum = 0.0f;

    // ---- staging: 180 segments (+ dup of p-halves), 3 passes
    #pragma unroll
    for (int pass = 0; pass < 3; ++pass) {
        int s = lane + 64 * pass;
        if (s < 180) {
            int A, NS, B, rel;
            if (s < 64)       { A = 0;  NS = 32; B = 0;   rel = s; }
            else if (s < 80)  { A = 33; NS = 8;  B = 96;  rel = s - 64; }
            else if (s < 96)  { A = 42; NS = 8;  B = 121; rel = s - 80; }
            else if (s < 112) { A = 51; NS = 8;  B = 146; rel = s - 96; }
            else if (s < 126) { A = 60; NS = 7;  B = 171; rel = s - 112; }
            else if (s < 140) { A = 68; NS = 7;  B = 193; rel = s - 126; }
            else if (s < 162) { A = 76; NS = 11; B = 215; rel = s - 140; }
            else              { A = 88; NS = 9;  B = 248; rel = s - 162; }
            bool isg = rel >= NS;
            int a = A + (isg ? rel - NS : rel);
            const float2* src = isg ? g : p;
            float2 q0 = src[a];
            float2 q1 = src[a + 1];
            float cx = 0.5f * (q0.x + q1.x) * CSCALE;
            float cy = 0.5f * (q0.y + q1.y) * CSCALE;
            float tx = q1.x - q0.x;
            float ty = q1.y - q0.y;
            if (isg) { tx = -tx; ty = -ty; }
            float4 v = make_float4(cx, cy, tx, ty);
            sg[B + rel] = v;
            if (!isg) sg[B + 2 * NS + rel] = v;   // dup first half (p-segs)
            accS += tx * tx + ty * ty;            // diagonal terms (w=1)
        }
    }
    if (lane < 5) sg[275 + lane] = make_float4(0.f, 0.f, 0.f, 0.f);

    // ---- landmark mean distance
    #pragma unroll
    for (int pass = 0; pass < 2; ++pass) {
        int t = lane + 64 * pass;
        if (t < NPT) {
            float2 pp = p[t];
            float2 gg = g[t];
            float dx = pp.x - gg.x;
            float dy = pp.y - gg.y;
            dsum += sqrtf(dx * dx + dy * dy);
        }
    }

    __syncthreads();  // single wave: degenerates to a waitcnt

    // ---- phase A: curve 0 (M=64), circulant, wrap-free via dup
    {
        const float4* sp = sg + lane;
        float4 sj = sp[0];
        #pragma unroll 8          // cap in-flight float4 loads (VGPR pressure)
        for (int t = 1; t <= 31; ++t) accD += pair_term(sp[t], sj);  // x2
        accS += pair_term(sp[32], sj);                               // x1
    }

    // ---- phase B plan 1: c1,c2,c3 (M=16) + c4 (M=14), t=1..8
    {
        int addr; float hp1;
        if (lane < 16)      { addr = 96 + lane;         hp1 = 9.f; }
        else if (lane < 32) { addr = 121 + (lane - 16); hp1 = 9.f; }
        else if (lane < 48) { addr = 146 + (lane - 32); hp1 = 9.f; }
        else if (lane < 62) { addr = 171 + (lane - 48); hp1 = 8.f; }
        else                { addr = 0;                 hp1 = 0.f; }
        const float4* sp = sg + addr;
        float4 sj = sp[0];
        #pragma unroll 4
        for (int t = 1; t <= 8; ++t) {
            float m = fminf(fmaxf(hp1 - (float)t, 0.f), 2.f);
            accS = fmaf(m, pair_term(sp[t], sj), accS);
        }
    }

    // ---- phase B plan 2: c5 (M=14), c6 (M=22), c7 (M=18), t=1..11
    {
        int addr; float hp1;
        if (lane < 14)      { addr = 193 + lane;        hp1 = 8.f;  }
        else if (lane < 36) { addr = 215 + (lane - 14); hp1 = 12.f; }
        else if (lane < 54) { addr = 248 + (lane - 36); hp1 = 10.f; }
        else                { addr = 0;                 hp1 = 0.f;  }
        const float4* sp = sg + addr;
        float4 sj = sp[0];
        #pragma unroll 4
        for (int t = 1; t <= 11; ++t) {
            float m = fminf(fmaxf(hp1 - (float)t, 0.f), 2.f);
            accS = fmaf(m, pair_term(sp[t], sj), accS);
        }
    }

    // per-lane combine, one wave reduction
    float v = 0.8f * dsum + 0.2f * (accS + 2.0f * accD);
    #pragma unroll
    for (int off = 32; off >= 1; off >>= 1) v += __shfl_xor(v, off, 64);

    if (lane == 0) {
        float ex = e0.x - e1.x;
        float ey = e0.y - e1.y;
        float eye = sqrtf(ex * ex + ey * ey);
        ws[b] = v / ((float)NPT * eye);
    }
}

__global__ __launch_bounds__(1024)
void lddmm_reduce(const float* __restrict__ ws, float* __restrict__ out,
                  int n4, float invbatch) {
    __shared__ float sm[1024];
    const int t = threadIdx.x;
    const float4* w4 = (const float4*)ws;
    float s = 0.0f;
    for (int i = t; i < n4; i += 1024) {
        float4 v = w4[i];
        s += (v.x + v.y) + (v.z + v.w);
    }
    sm[t] = s;
    __syncthreads();
    for (int off = 512; off >= 1; off >>= 1) {
        if (t < off) sm[t] += sm[t + off];
        __syncthreads();
    }
    if (t == 0) out[0] = sm[0] * invbatch;
}

extern "C" void kernel_launch(void* const* d_in, const int* in_sizes, int n_in,
                              void* d_out, int out_size, void* d_ws, size_t ws_size,
                              hipStream_t stream) {
    const float* pred = (const float*)d_in[0];
    const float* gt = (const float*)d_in[1];
    float* out = (float*)d_out;
    float* ws = (float*)d_ws;
    const int batch = in_sizes[0] / (2 * NPT);

    lddmm_main<<<batch, 64, 0, stream>>>(pred, gt, ws);
    lddmm_reduce<<<1, 1024, 0, stream>>>(ws, out, batch / 4, 1.0f / (float)batch);
}

// Round 5
// 28.185 us; speedup vs baseline: 9.5229x; 1.0436x over previous
//
#include <hip/hip_runtime.h>
#include <math.h>

static constexpr int NPT = 98;
static constexpr int SEGSLOTS = 288;    // 275 used + zero pad [275,288)
static constexpr float CSCALE = 0.310128480f;       // sqrt(log2(e)/15)
static constexpr float CSCALE_HALF = 0.155064240f;  // 0.5 * CSCALE

#if __has_builtin(__builtin_amdgcn_exp2f)
#define EXP2F(x) __builtin_amdgcn_exp2f(x)
#else
#define EXP2F(x) exp2f(x)
#endif
#if __has_builtin(__builtin_amdgcn_sqrtf)
#define SQRTF(x) __builtin_amdgcn_sqrtf(x)
#else
#define SQRTF(x) sqrtf(x)
#endif

typedef float v2f __attribute__((ext_vector_type(2)));
typedef float v4f __attribute__((ext_vector_type(4)));
typedef float v4fu __attribute__((ext_vector_type(4), aligned(8)));  // 8B-aligned 16B load

// LDS layout (v4f slots {cx,cy,tx,ty}), one batch element per 64-thread block.
// Each curve: M segments + dup of first M/2 (wrap-free circulant reads).
//  c0: base   0, M=64 -> [0,96)     c4: base 171, M=14 -> [171,192)
//  c1: base  96, M=16 -> [96,120)   c5: base 193, M=14 -> [193,214)
//  c2: base 121, M=16 -> [121,145)  c6: base 215, M=22 -> [215,248)
//  c3: base 146, M=16 -> [146,170)  c7: base 248, M=18 -> [248,275)
// Zero pad [275,288): idle-lane sj (tau=0 => term=0) and m=0 overruns.

__device__ __forceinline__ float pair_term(v4f si, v4f sj) {
    v2f dc = si.xy - sj.xy;        // v_pk_add (neg)
    v2f sq = dc * dc;              // v_pk_mul
    float d2 = sq.x + sq.y;        // pre-scaled by log2e/sigma
    v2f tp = si.zw * sj.zw;        // v_pk_mul
    float dt = tp.x + tp.y;
    return EXP2F(-d2) * dt;
}

__global__ __launch_bounds__(64, 5)   // cap 102 VGPR (natural ~90) -> no spill
void lddmm_main(const float* __restrict__ pred, const float* __restrict__ gt,
                float* __restrict__ ws) {
    __shared__ v4f sg[SEGSLOTS];
    const int lane = threadIdx.x;
    const int b = blockIdx.x;

    const float* pf = pred + (size_t)b * (2 * NPT);
    const float* gf = gt + (size_t)b * (2 * NPT);
    const v2f* p2 = (const v2f*)pf;
    const v2f* g2 = (const v2f*)gf;

    // eye-corner loads issued early (consumed at the very end)
    v2f e0 = g2[60];
    v2f e1 = g2[72];

    float accS = 0.0f;   // x1 bucket
    float accD = 0.0f;   // x2 bucket
    float dsum = 0.0f;

    // ---- staging: 180 segments (+ dup of p-halves), 3 passes
    #pragma unroll
    for (int pass = 0; pass < 3; ++pass) {
        int s = lane + 64 * pass;
        if (s < 180) {
            int A, NS, B, rel;
            if (s < 64)       { A = 0;  NS = 32; B = 0;   rel = s; }
            else if (s < 80)  { A = 33; NS = 8;  B = 96;  rel = s - 64; }
            else if (s < 96)  { A = 42; NS = 8;  B = 121; rel = s - 80; }
            else if (s < 112) { A = 51; NS = 8;  B = 146; rel = s - 96; }
            else if (s < 126) { A = 60; NS = 7;  B = 171; rel = s - 112; }
            else if (s < 140) { A = 68; NS = 7;  B = 193; rel = s - 126; }
            else if (s < 162) { A = 76; NS = 11; B = 215; rel = s - 140; }
            else              { A = 88; NS = 9;  B = 248; rel = s - 162; }
            bool isg = rel >= NS;
            int a = A + (isg ? rel - NS : rel);
            const float* src = isg ? gf : pf;
            v4fu q = *(const v4fu*)(src + 2 * a);   // {x0,y0,x1,y1} one 16B load
            v2f c = (q.xy + q.zw) * CSCALE_HALF;
            v2f tau = q.zw - q.xy;
            float sgn = isg ? -1.0f : 1.0f;
            tau *= sgn;
            v4f v = {c.x, c.y, tau.x, tau.y};
            sg[B + rel] = v;
            if (!isg) sg[B + 2 * NS + rel] = v;     // dup first half (p-segs)
            accS = fmaf(tau.x, tau.x, accS);        // diagonal terms (w=1)
            accS = fmaf(tau.y, tau.y, accS);
        }
    }
    if (lane < 13) sg[275 + lane] = (v4f){0.f, 0.f, 0.f, 0.f};

    // ---- landmark mean distance
    #pragma unroll
    for (int pass = 0; pass < 2; ++pass) {
        int t = lane + 64 * pass;
        if (t < NPT) {
            v2f d = p2[t] - g2[t];
            v2f s = d * d;
            dsum += SQRTF(s.x + s.y);
        }
    }

    __syncthreads();  // single wave: degenerates to a waitcnt

    // ---- phase A: curve 0 (M=64), circulant, wrap-free via dup
    {
        const v4f* sp = sg + lane;
        v4f sj = sp[0];
        #pragma unroll 8
        for (int t = 1; t <= 31; ++t) accD += pair_term(sp[t], sj);  // x2
        accS += pair_term(sp[32], sj);                               // x1
    }

    // ---- phase B plan 1: c1,c2,c3 (M=16) + c4 (M=14)
    {
        int addr; float hp1;
        if (lane < 16)      { addr = 96 + lane;         hp1 = 9.f; }
        else if (lane < 32) { addr = 121 + (lane - 16); hp1 = 9.f; }
        else if (lane < 48) { addr = 146 + (lane - 32); hp1 = 9.f; }
        else if (lane < 62) { addr = 171 + (lane - 48); hp1 = 8.f; }
        else                { addr = 275;               hp1 = 0.f; }  // zero pad
        const v4f* sp = sg + addr;
        v4f sj = sp[0];
        #pragma unroll
        for (int t = 1; t <= 6; ++t) accD += pair_term(sp[t], sj);   // w=2 uniform
        #pragma unroll
        for (int t = 7; t <= 8; ++t) {                                // edge weights
            float m = fminf(fmaxf(hp1 - (float)t, 0.f), 2.f);
            accS = fmaf(m, pair_term(sp[t], sj), accS);
        }
    }

    // ---- phase B plan 2: c5 (M=14), c6 (M=22), c7 (M=18)
    {
        int addr; float hp1;
        if (lane < 14)      { addr = 193 + lane;        hp1 = 8.f;  }
        else if (lane < 36) { addr = 215 + (lane - 14); hp1 = 12.f; }
        else if (lane < 54) { addr = 248 + (lane - 36); hp1 = 10.f; }
        else                { addr = 275;               hp1 = 0.f;  } // zero pad
        const v4f* sp = sg + addr;
        v4f sj = sp[0];
        #pragma unroll
        for (int t = 1; t <= 6; ++t) accD += pair_term(sp[t], sj);   // w=2 uniform
        #pragma unroll
        for (int t = 7; t <= 11; ++t) {                               // edge weights
            float m = fminf(fmaxf(hp1 - (float)t, 0.f), 2.f);
            accS = fmaf(m, pair_term(sp[t], sj), accS);
        }
    }

    // per-lane combine, one wave reduction
    float v = 0.8f * dsum + 0.2f * (accS + 2.0f * accD);
    #pragma unroll
    for (int off = 32; off >= 1; off >>= 1) v += __shfl_xor(v, off, 64);

    if (lane == 0) {
        v2f de = e0 - e1;
        v2f s = de * de;
        float eye = SQRTF(s.x + s.y);
        ws[b] = v / ((float)NPT * eye);
    }
}

__global__ __launch_bounds__(1024)
void lddmm_reduce(const float* __restrict__ ws, float* __restrict__ out,
                  int n4, float invbatch) {
    __shared__ float sm[1024];
    const int t = threadIdx.x;
    const float4* w4 = (const float4*)ws;
    float s = 0.0f;
    for (int i = t; i < n4; i += 1024) {
        float4 v = w4[i];
        s += (v.x + v.y) + (v.z + v.w);
    }
    sm[t] = s;
    __syncthreads();
    for (int off = 512; off >= 1; off >>= 1) {
        if (t < off) sm[t] += sm[t + off];
        __syncthreads();
    }
    if (t == 0) out[0] = sm[0] * invbatch;
}

extern "C" void kernel_launch(void* const* d_in, const int* in_sizes, int n_in,
                              void* d_out, int out_size, void* d_ws, size_t ws_size,
                              hipStream_t stream) {
    const float* pred = (const float*)d_in[0];
    const float* gt = (const float*)d_in[1];
    float* out = (float*)d_out;
    float* ws = (float*)d_ws;
    const int batch = in_sizes[0] / (2 * NPT);

    lddmm_main<<<batch, 64, 0, stream>>>(pred, gt, ws);
    lddmm_reduce<<<1, 1024, 0, stream>>>(ws, out, batch / 4, 1.0f / (float)batch);
}

// Round 7
// 26.617 us; speedup vs baseline: 10.0839x; 1.0589x over previous
//
#include <hip/hip_runtime.h>
#include <math.h>

static constexpr int NPT = 98;
static constexpr float CSCALE_HALF = 0.155064240f;  // 0.5 * sqrt(log2(e)/15)

#if __has_builtin(__builtin_amdgcn_exp2f)
#define EXP2F(x) __builtin_amdgcn_exp2f(x)
#else
#define EXP2F(x) exp2f(x)
#endif
#if __has_builtin(__builtin_amdgcn_sqrtf)
#define SQRTF(x) __builtin_amdgcn_sqrtf(x)
#else
#define SQRTF(x) sqrtf(x)
#endif

typedef float v2f __attribute__((ext_vector_type(2)));
typedef float v4a __attribute__((ext_vector_type(4)));               // 16B aligned
typedef float v4fu __attribute__((ext_vector_type(4), aligned(8)));  // 8B aligned
typedef _Float16 h2 __attribute__((ext_vector_type(2)));
typedef _Float16 h4 __attribute__((ext_vector_type(4)));

#if __has_builtin(__builtin_amdgcn_fdot2)
#define FDOT2(a, b, c) __builtin_amdgcn_fdot2((a), (b), (c), false)
#else
#define FDOT2(a, b, c) fmaf((float)(a).x, (float)(b).x, fmaf((float)(a).y, (float)(b).y, (c)))
#endif

#if __has_builtin(__builtin_amdgcn_cvt_pkrtz)
#define PKRTZ(x, y) __builtin_bit_cast(h2, __builtin_amdgcn_cvt_pkrtz((x), (y)))
#else
static __device__ __forceinline__ h2 PKRTZ(float x, float y) {
    h2 r; r.x = (_Float16)x; r.y = (_Float16)y; return r;
}
#endif

// ---- LDS layout (h4 slots {cx,cy,tx,ty}, f16, 8B each) ----
// Each curve stored circularly: M=2h segments + dup of first DUPN
// (c0: DUPN=32, others: 6) so all circulant reads are wrap-free.
//  c0: base   0, M=64, dup[64,96)     c4: base 162, M=14, dup 6 -> [162,182)
//  c1: base  96, M=16, dup 6 -> [96,118)   c5: base 182, M=14 -> [182,202)
//  c2: base 118, M=16 -> [118,140)         c6: base 202, M=22 -> [202,230)
//  c3: base 140, M=16 -> [140,162)         c7: base 230, M=18 -> [230,254)
//
// Two-column circulant: lane holds cols {j, j+h} (h = M/2). Read at offset
// t serves class t (vs col j) and class h-t (vs col j+h). Unordered sum
// U = sum_{t=1..h-1} C(t) + 1/2 C(h); curve total = diag + 2U.

__device__ __forceinline__ float wdt(h4 si, h4 sj) {
    h2 dc = si.xy - sj.xy;                         // v_pk_add_f16
    float d2 = FDOT2(dc, dc, 0.0f);                // v_dot2_f32_f16 (pre-scaled)
    float dt = FDOT2(si.zw, sj.zw, 0.0f);
    return EXP2F(-d2) * dt;
}

__global__ __launch_bounds__(64, 6)
void lddmm_main(const float* __restrict__ pred, const float* __restrict__ gt,
                float* __restrict__ ws) {
    __shared__ h4 sh[256];
    const int lane = threadIdx.x;
    const int b = blockIdx.x;

    const float* pf = pred + (size_t)b * (2 * NPT);
    const float* gf = gt + (size_t)b * (2 * NPT);
    const v2f* g2 = (const v2f*)gf;

    // eye-corner loads issued early (consumed at the very end)
    v2f e0 = g2[60];
    v2f e1 = g2[72];

    float diag = 0.0f;    // class-0: sum |tau|^2 (f32, exact)
    float accS = 0.0f;    // x1 bucket (c0 mirror C(32))
    float accA = 0.0f;    // x2 bucket, chain A
    float accB = 0.0f;    // x2 bucket, chain B
    float dsum = 0.0f;

    // ---- staging: 180 segments in f16 (+ wrap dups), 3 passes
    #pragma unroll
    for (int pass = 0; pass < 3; ++pass) {
        int s = lane + 64 * pass;
        if (s < 180) {
            int A, NS, B, rel;
            if (s < 64)       { A = 0;  NS = 32; B = 0;   rel = s; }
            else if (s < 80)  { A = 33; NS = 8;  B = 96;  rel = s - 64; }
            else if (s < 96)  { A = 42; NS = 8;  B = 118; rel = s - 80; }
            else if (s < 112) { A = 51; NS = 8;  B = 140; rel = s - 96; }
            else if (s < 126) { A = 60; NS = 7;  B = 162; rel = s - 112; }
            else if (s < 140) { A = 68; NS = 7;  B = 182; rel = s - 126; }
            else if (s < 162) { A = 76; NS = 11; B = 202; rel = s - 140; }
            else              { A = 88; NS = 9;  B = 230; rel = s - 162; }
            bool isg = rel >= NS;
            int a = A + (isg ? rel - NS : rel);
            const float* src = isg ? gf : pf;
            v4fu q = *(const v4fu*)(src + 2 * a);   // {x0,y0,x1,y1}
            v2f c = (q.xy + q.zw) * CSCALE_HALF;
            v2f tau = q.zw - q.xy;
            if (isg) tau = -tau;
            diag = fmaf(tau.x, tau.x, diag);
            diag = fmaf(tau.y, tau.y, diag);
            h2 ch = PKRTZ(c.x, c.y);
            h2 th = PKRTZ(tau.x, tau.y);
            h4 v; v.x = ch.x; v.y = ch.y; v.z = th.x; v.w = th.y;
            sh[B + rel] = v;
            int DUPN = (B == 0) ? 32 : 6;
            if (rel < DUPN) sh[B + 2 * NS + rel] = v;   // circular dup
        }
    }

    // ---- landmark mean distance (f32, one float4 pass: 2 points/lane)
    if (lane < 49) {
        v4a p4 = *(const v4a*)(pf + 4 * lane);
        v4a g4 = *(const v4a*)(gf + 4 * lane);
        v2f d0 = p4.xy - g4.xy;
        v2f d1 = p4.zw - g4.zw;
        dsum = SQRTF(d0.x * d0.x + d0.y * d0.y) + SQRTF(d1.x * d1.x + d1.y * d1.y);
    }

    __syncthreads();  // single wave: cheap

    // ---- phase A: curve 0 (M=64, h=32), cols {lane, lane+32}
    // reads t=1..16: class t (sjA) + class 32-t (sjB, masked at t=16)
    {
        h4 sjA = sh[lane];
        h4 sjB = sh[lane + 32];
        #pragma unroll 5
        for (int t = 1; t <= 15; ++t) {
            h4 r = sh[lane + t];
            accA += wdt(r, sjA);
            accB += wdt(r, sjB);
        }
        { h4 r = sh[lane + 16]; accA += wdt(r, sjA); }  // t=16: sjA only
        accS += wdt(sjA, sjB);   // mirror: sum over 64 lanes = C(32) -> x1
    }

    // ---- phase B: curves c1..c7 (58 lanes), cols {jl, jl+h} per curve
    // step t: u1=sp[t] (cls t vs A, cls h-t vs B), u2=sp[h+t] (cls t vs B,
    // cls h-t vs A). mA=(t<=ceil((h-1)/2)), mB=(t<=floor((h-1)/2)).
    {
        int base, jl, h, TA, TB; float mm;
        if      (lane < 8)  { base = 96;  jl = lane;      h = 8;  TA = 4; TB = 3; mm = 1.f; }
        else if (lane < 16) { base = 118; jl = lane - 8;  h = 8;  TA = 4; TB = 3; mm = 1.f; }
        else if (lane < 24) { base = 140; jl = lane - 16; h = 8;  TA = 4; TB = 3; mm = 1.f; }
        else if (lane < 31) { base = 162; jl = lane - 24; h = 7;  TA = 3; TB = 3; mm = 1.f; }
        else if (lane < 38) { base = 182; jl = lane - 31; h = 7;  TA = 3; TB = 3; mm = 1.f; }
        else if (lane < 49) { base = 202; jl = lane - 38; h = 11; TA = 5; TB = 5; mm = 1.f; }
        else if (lane < 58) { base = 230; jl = lane - 49; h = 9;  TA = 4; TB = 4; mm = 1.f; }
        else                { base = 202; jl = 0;         h = 11; TA = 0; TB = 0; mm = 0.f; }
        const h4* sp = sh + base + jl;
        h4 sjA = sp[0];
        h4 sjB = sp[h];
        accA = fmaf(mm, wdt(sjA, sjB), accA);   // mirror = 1/2 C(h) -> x2
        #pragma unroll
        for (int t = 1; t <= 5; ++t) {
            h4 u1 = sp[t];
            h4 u2 = sp[h + t];
            float mA = (t <= TA) ? 1.0f : 0.0f;
            float mB = (t <= TB) ? 1.0f : 0.0f;
            accA = fmaf(mA, wdt(u1, sjA) + wdt(u2, sjB), accA);  // C(t)
            accB = fmaf(mB, wdt(u1, sjB) + wdt(u2, sjA), accB);  // C(h-t)
        }
    }

    // curve total = diag + accS + 2*(accA+accB); combine with landmark term
    float v = 0.8f * dsum + 0.2f * (fmaf(2.0f, accA + accB, diag + accS));
    #pragma unroll
    for (int off = 32; off >= 1; off >>= 1) v += __shfl_xor(v, off, 64);

    if (lane == 0) {
        v2f de = e0 - e1;
        float eye = SQRTF(de.x * de.x + de.y * de.y);
        ws[b] = v / ((float)NPT * eye);
    }
}

__global__ __launch_bounds__(1024)
void lddmm_reduce(const float* __restrict__ ws, float* __restrict__ out,
                  int n4, float invbatch) {
    __shared__ float sm[1024];
    const int t = threadIdx.x;
    const float4* w4 = (const float4*)ws;
    float s = 0.0f;
    for (int i = t; i < n4; i += 1024) {
        float4 v = w4[i];
        s += (v.x + v.y) + (v.z + v.w);
    }
    sm[t] = s;
    __syncthreads();
    for (int off = 512; off >= 1; off >>= 1) {
        if (t < off) sm[t] += sm[t + off];
        __syncthreads();
    }
    if (t == 0) out[0] = sm[0] * invbatch;
}

extern "C" void kernel_launch(void* const* d_in, const int* in_sizes, int n_in,
                              void* d_out, int out_size, void* d_ws, size_t ws_size,
                              hipStream_t stream) {
    const float* pred = (const float*)d_in[0];
    const float* gt = (const float*)d_in[1];
    float* out = (float*)d_out;
    float* ws = (float*)d_ws;
    const int batch = in_sizes[0] / (2 * NPT);

    lddmm_main<<<batch, 64, 0, stream>>>(pred, gt, ws);
    lddmm_reduce<<<1, 1024, 0, stream>>>(ws, out, batch / 4, 1.0f / (float)batch);
}

// Round 8
// 26.378 us; speedup vs baseline: 10.1752x; 1.0090x over previous
//
#include <hip/hip_runtime.h>
#include <math.h>

static constexpr int NPT = 98;
static constexpr float CSCALE_HALF = 0.155064240f;  // 0.5 * sqrt(log2(e)/15)

#if __has_builtin(__builtin_amdgcn_exp2f)
#define EXP2F(x) __builtin_amdgcn_exp2f(x)
#else
#define EXP2F(x) exp2f(x)
#endif
#if __has_builtin(__builtin_amdgcn_sqrtf)
#define SQRTF(x) __builtin_amdgcn_sqrtf(x)
#else
#define SQRTF(x) sqrtf(x)
#endif

typedef float v2f __attribute__((ext_vector_type(2)));
typedef float v4a __attribute__((ext_vector_type(4)));               // 16B aligned
typedef float v4fu __attribute__((ext_vector_type(4), aligned(8)));  // 8B aligned
typedef _Float16 h2 __attribute__((ext_vector_type(2)));
typedef _Float16 h4 __attribute__((ext_vector_type(4)));

#if __has_builtin(__builtin_amdgcn_fdot2)
#define FDOT2(a, b, c) __builtin_amdgcn_fdot2((a), (b), (c), false)
#else
#define FDOT2(a, b, c) fmaf((float)(a).x, (float)(b).x, fmaf((float)(a).y, (float)(b).y, (c)))
#endif

#if __has_builtin(__builtin_amdgcn_cvt_pkrtz)
#define PKRTZ(x, y) __builtin_bit_cast(h2, __builtin_amdgcn_cvt_pkrtz((x), (y)))
#else
static __device__ __forceinline__ h2 PKRTZ(float x, float y) {
    h2 r; r.x = (_Float16)x; r.y = (_Float16)y; return r;
}
#endif

// ---- Per-wave LDS slice (h4 slots {cx,cy,tx,ty}, f16, 8B each) ----
// Each curve stored circularly: M=2h segments + dup of first DUPN
// (c0: DUPN=32, others: 6) so all circulant reads are wrap-free.
//  c0: base   0, M=64, dup[64,96)          c4: base 162, M=14 -> [162,182)
//  c1: base  96, M=16, dup 6 -> [96,118)   c5: base 182, M=14 -> [182,202)
//  c2: base 118, M=16 -> [118,140)         c6: base 202, M=22 -> [202,230)
//  c3: base 140, M=16 -> [140,162)         c7: base 230, M=18 -> [230,254)
//
// Two-column circulant: lane holds cols {j, j+h} (h = M/2). Read at offset
// t serves class t (vs col j) and class h-t (vs col j+h). Unordered sum
// U = sum_{t=1..h-1} C(t) + 1/2 C(h); curve total = diag + 2U.
//
// 4 waves/block, one batch element per wave, NO block barrier: staging->
// read dependency is wave-internal, fenced by s_waitcnt lgkmcnt(0).

__device__ __forceinline__ float wdt(h4 si, h4 sj) {
    h2 dc = si.xy - sj.xy;                         // v_pk_add_f16
    float d2 = FDOT2(dc, dc, 0.0f);                // v_dot2_f32_f16 (pre-scaled)
    float dt = FDOT2(si.zw, sj.zw, 0.0f);
    return EXP2F(-d2) * dt;
}

__global__ __launch_bounds__(256, 8)   // cap 64 VGPR -> 32 waves/CU possible
void lddmm_main(const float* __restrict__ pred, const float* __restrict__ gt,
                float* __restrict__ ws) {
    __shared__ h4 sh[4][256];
    const int wave = threadIdx.x >> 6;
    const int lane = threadIdx.x & 63;
    const int b = blockIdx.x * 4 + wave;

    const float* pf = pred + (size_t)b * (2 * NPT);
    const float* gf = gt + (size_t)b * (2 * NPT);
    const v2f* g2 = (const v2f*)gf;
    h4* sw = sh[wave];

    // eye-corner loads issued early (consumed at the very end)
    v2f e0 = g2[60];
    v2f e1 = g2[72];

    float diag = 0.0f;    // class-0: sum |tau|^2 (f32, exact)
    float accS = 0.0f;    // x1 bucket (c0 mirror C(32))
    float accA = 0.0f;    // x2 bucket, chain A
    float accB = 0.0f;    // x2 bucket, chain B
    float dsum = 0.0f;

    // ---- staging: 180 segments in f16 (+ wrap dups), 3 passes
    #pragma unroll
    for (int pass = 0; pass < 3; ++pass) {
        int s = lane + 64 * pass;
        if (s < 180) {
            int A, NS, B, rel;
            if (s < 64)       { A = 0;  NS = 32; B = 0;   rel = s; }
            else if (s < 80)  { A = 33; NS = 8;  B = 96;  rel = s - 64; }
            else if (s < 96)  { A = 42; NS = 8;  B = 118; rel = s - 80; }
            else if (s < 112) { A = 51; NS = 8;  B = 140; rel = s - 96; }
            else if (s < 126) { A = 60; NS = 7;  B = 162; rel = s - 112; }
            else if (s < 140) { A = 68; NS = 7;  B = 182; rel = s - 126; }
            else if (s < 162) { A = 76; NS = 11; B = 202; rel = s - 140; }
            else              { A = 88; NS = 9;  B = 230; rel = s - 162; }
            bool isg = rel >= NS;
            int a = A + (isg ? rel - NS : rel);
            const float* src = isg ? gf : pf;
            v4fu q = *(const v4fu*)(src + 2 * a);   // {x0,y0,x1,y1}
            v2f c = (q.xy + q.zw) * CSCALE_HALF;
            v2f tau = q.zw - q.xy;
            if (isg) tau = -tau;
            diag = fmaf(tau.x, tau.x, diag);
            diag = fmaf(tau.y, tau.y, diag);
            h2 ch = PKRTZ(c.x, c.y);
            h2 th = PKRTZ(tau.x, tau.y);
            h4 v; v.x = ch.x; v.y = ch.y; v.z = th.x; v.w = th.y;
            sw[B + rel] = v;
            int DUPN = (B == 0) ? 32 : 6;
            if (rel < DUPN) sw[B + 2 * NS + rel] = v;   // circular dup
        }
    }

    // ---- landmark mean distance (f32, one float4 pass: 2 points/lane)
    if (lane < 49) {
        v4a p4 = *(const v4a*)(pf + 4 * lane);
        v4a g4 = *(const v4a*)(gf + 4 * lane);
        v2f d0 = p4.xy - g4.xy;
        v2f d1 = p4.zw - g4.zw;
        dsum = SQRTF(d0.x * d0.x + d0.y * d0.y) + SQRTF(d1.x * d1.x + d1.y * d1.y);
    }

    // wave-local LDS fence: this wave's ds_writes complete before its reads.
    // (All consumers are this wave's lanes; no block barrier needed.)
    asm volatile("s_waitcnt lgkmcnt(0)" ::: "memory");

    // ---- phase A: curve 0 (M=64, h=32), cols {lane, lane+32}
    // reads t=1..16: class t (sjA) + class 32-t (sjB, masked at t=16)
    {
        h4 sjA = sw[lane];
        h4 sjB = sw[lane + 32];
        #pragma unroll 4
        for (int t = 1; t <= 15; ++t) {
            h4 r = sw[lane + t];
            accA += wdt(r, sjA);
            accB += wdt(r, sjB);
        }
        { h4 r = sw[lane + 16]; accA += wdt(r, sjA); }  // t=16: sjA only
        accS += wdt(sjA, sjB);   // mirror: sum over 64 lanes = C(32) -> x1
    }

    // ---- phase B: curves c1..c7 (58 lanes), cols {jl, jl+h} per curve
    // step t: u1=sp[t] (cls t vs A, cls h-t vs B), u2=sp[h+t] (cls t vs B,
    // cls h-t vs A). mA=(t<=ceil((h-1)/2)), mB=(t<=floor((h-1)/2)).
    {
        int base, jl, h, TA, TB; float mm;
        if      (lane < 8)  { base = 96;  jl = lane;      h = 8;  TA = 4; TB = 3; mm = 1.f; }
        else if (lane < 16) { base = 118; jl = lane - 8;  h = 8;  TA = 4; TB = 3; mm = 1.f; }
        else if (lane < 24) { base = 140; jl = lane - 16; h = 8;  TA = 4; TB = 3; mm = 1.f; }
        else if (lane < 31) { base = 162; jl = lane - 24; h = 7;  TA = 3; TB = 3; mm = 1.f; }
        else if (lane < 38) { base = 182; jl = lane - 31; h = 7;  TA = 3; TB = 3; mm = 1.f; }
        else if (lane < 49) { base = 202; jl = lane - 38; h = 11; TA = 5; TB = 5; mm = 1.f; }
        else if (lane < 58) { base = 230; jl = lane - 49; h = 9;  TA = 4; TB = 4; mm = 1.f; }
        else                { base = 202; jl = 0;         h = 11; TA = 0; TB = 0; mm = 0.f; }
        const h4* sp = sw + base + jl;
        h4 sjA = sp[0];
        h4 sjB = sp[h];
        accA = fmaf(mm, wdt(sjA, sjB), accA);   // mirror = 1/2 C(h) -> x2
        #pragma unroll
        for (int t = 1; t <= 5; ++t) {
            h4 u1 = sp[t];
            h4 u2 = sp[h + t];
            float mA = (t <= TA) ? 1.0f : 0.0f;
            float mB = (t <= TB) ? 1.0f : 0.0f;
            accA = fmaf(mA, wdt(u1, sjA) + wdt(u2, sjB), accA);  // C(t)
            accB = fmaf(mB, wdt(u1, sjB) + wdt(u2, sjA), accB);  // C(h-t)
        }
    }

    // curve total = diag + accS + 2*(accA+accB); combine with landmark term
    float v = 0.8f * dsum + 0.2f * (fmaf(2.0f, accA + accB, diag + accS));
    #pragma unroll
    for (int off = 32; off >= 1; off >>= 1) v += __shfl_xor(v, off, 64);

    if (lane == 0) {
        v2f de = e0 - e1;
        float eye = SQRTF(de.x * de.x + de.y * de.y);
        ws[b] = v / ((float)NPT * eye);
    }
}

__global__ __launch_bounds__(1024)
void lddmm_reduce(const float* __restrict__ ws, float* __restrict__ out,
                  int n4, float invbatch) {
    __shared__ float sm[1024];
    const int t = threadIdx.x;
    const float4* w4 = (const float4*)ws;
    float s = 0.0f;
    for (int i = t; i < n4; i += 1024) {
        float4 v = w4[i];
        s += (v.x + v.y) + (v.z + v.w);
    }
    sm[t] = s;
    __syncthreads();
    for (int off = 512; off >= 1; off >>= 1) {
        if (t < off) sm[t] += sm[t + off];
        __syncthreads();
    }
    if (t == 0) out[0] = sm[0] * invbatch;
}

extern "C" void kernel_launch(void* const* d_in, const int* in_sizes, int n_in,
                              void* d_out, int out_size, void* d_ws, size_t ws_size,
                              hipStream_t stream) {
    const float* pred = (const float*)d_in[0];
    const float* gt = (const float*)d_in[1];
    float* out = (float*)d_out;
    float* ws = (float*)d_ws;
    const int batch = in_sizes[0] / (2 * NPT);

    lddmm_main<<<batch / 4, 256, 0, stream>>>(pred, gt, ws);
    lddmm_reduce<<<1, 1024, 0, stream>>>(ws, out, batch / 4, 1.0f / (float)batch);
}